// Round 6
// baseline (2802.274 us; speedup 1.0000x reference)
//
#include <hip/hip_runtime.h>
#include <stdint.h>

#define PN 24564
#define BN 64
#define MN 32
#define CN 81
#define MG 4       // gt boxes per block in k_gt_best

typedef float f4 __attribute__((ext_vector_type(4)));
typedef unsigned long long u64;
typedef unsigned int u32;

// ---------------- workspace layout ----------------
constexpr size_t SZ_BP4   = (size_t)BN * PN * 4;        // 6,288,384
constexpr size_t OFF_OVL  = SZ_BP4;                     // best_ovl f32
constexpr size_t OFF_IDX  = 2 * SZ_BP4;                 // best_idx i32
constexpr size_t OFF_PACK = 3 * SZ_BP4;                 // packed u64 [BN*MN]
constexpr size_t SZ_PACK  = (size_t)BN * MN * 8;        // 16,384
constexpr size_t OFF_PCNT = OFF_PACK + SZ_PACK;         // per-batch pos count (BN i32)
constexpr size_t OFF_NP   = OFF_PCNT + BN * 4;          // global num_pos
constexpr size_t OFF_ACC  = OFF_NP + 8;                 // 3 doubles
constexpr size_t ZERO_OFF = OFF_PCNT;
constexpr size_t ZERO_WORDS = (BN * 4 + 8 + 24) / 4;    // 72 u32 words

__device__ __forceinline__ float sl1f(float d) {
  float ad = fabsf(d);
  return ad < 1.0f ? 0.5f * d * d : ad - 0.5f;
}

__device__ __forceinline__ u64 shfl_xor_u64(u64 v, int m) {
  u32 lo = (u32)v, hi = (u32)(v >> 32);
  lo = (u32)__shfl_xor((int)lo, m, 64);
  hi = (u32)__shfl_xor((int)hi, m, 64);
  return ((u64)hi << 32) | lo;
}

// ---------------- K0: zero the accumulator tail ----------------
__global__ void k_zero(u32* __restrict__ tail)
{
  if (threadIdx.x < ZERO_WORDS) tail[threadIdx.x] = 0u;
}

// ---------------- K1a: per-prior best gt (max/argmax over m) ----------------
__global__ __launch_bounds__(256)
void k_prior_best(const f4* __restrict__ priors,
                  const f4* __restrict__ gt_boxes,
                  float* __restrict__ best_ovl,
                  int* __restrict__ best_idx)
{
  const int b = blockIdx.y;
  const int tid = threadIdx.x;
  __shared__ f4 gt[MN];
  __shared__ float ga[MN];
  if (tid < MN) {
    f4 g = gt_boxes[b * MN + tid];
    gt[tid] = g;
    ga[tid] = (g.z - g.x) * (g.w - g.y);
  }
  __syncthreads();
  const int p = blockIdx.x * 256 + tid;
  if (p >= PN) return;
  f4 pr = priors[p];
  float px0 = pr.x - pr.z * 0.5f;
  float py0 = pr.y - pr.w * 0.5f;
  float px1 = pr.x + pr.z * 0.5f;
  float py1 = pr.y + pr.w * 0.5f;
  float pa  = (px1 - px0) * (py1 - py0);
  float bov = -1.0f; int bi = 0;
#pragma unroll
  for (int m = 0; m < MN; m++) {
    f4 g = gt[m];
    float iw = fmaxf(fminf(px1, g.z) - fmaxf(px0, g.x), 0.0f);
    float ih = fmaxf(fminf(py1, g.w) - fmaxf(py0, g.y), 0.0f);
    float inter = iw * ih;
    float iou = inter / (pa + ga[m] - inter);
    if (iou > bov) { bov = iou; bi = m; }
  }
  best_ovl[(size_t)b * PN + p] = bov;
  best_idx[(size_t)b * PN + p] = bi;
}

// ---------------- K1b: per-gt best prior (argmax over p), 4 gt per block ----
__global__ __launch_bounds__(256)
void k_gt_best(const f4* __restrict__ priors,
               const f4* __restrict__ gt_boxes,
               u64* __restrict__ packed_best)
{
  const int b = blockIdx.y;
  const int mbase = blockIdx.x * MG;
  const int tid = threadIdx.x;

  f4 g[MG]; float ga[MG];
#pragma unroll
  for (int j = 0; j < MG; j++) {
    g[j] = gt_boxes[b * MN + mbase + j];
    ga[j] = (g[j].z - g[j].x) * (g[j].w - g[j].y);
  }

  u64 best[MG];
#pragma unroll
  for (int j = 0; j < MG; j++) best[j] = 0ull;

  for (int p = tid; p < PN; p += 256) {
    f4 pr = priors[p];
    float px0 = pr.x - pr.z * 0.5f;
    float py0 = pr.y - pr.w * 0.5f;
    float px1 = pr.x + pr.z * 0.5f;
    float py1 = pr.y + pr.w * 0.5f;
    float pa  = (px1 - px0) * (py1 - py0);
    u32 key = 0xFFFFFFFFu - (u32)p;  // larger key = smaller p -> first-occurrence ties
#pragma unroll
    for (int j = 0; j < MG; j++) {
      float iw = fmaxf(fminf(px1, g[j].z) - fmaxf(px0, g[j].x), 0.0f);
      float ih = fmaxf(fminf(py1, g[j].w) - fmaxf(py0, g[j].y), 0.0f);
      float inter = iw * ih;
      float iou = inter / (pa + ga[j] - inter);
      u64 pk = ((u64)__float_as_uint(iou) << 32) | key;
      if (pk > best[j]) best[j] = pk;
    }
  }

  __shared__ u64 wred[4][MG];
  const int lane = tid & 63, wv = tid >> 6;
#pragma unroll
  for (int j = 0; j < MG; j++) {
    u64 v = best[j];
#pragma unroll
    for (int off = 1; off < 64; off <<= 1) {
      u64 o = shfl_xor_u64(v, off);
      if (o > v) v = o;
    }
    if (lane == 0) wred[wv][j] = v;
  }
  __syncthreads();
  if (tid < MG) {
    u64 v = wred[0][tid];
#pragma unroll
    for (int w = 1; w < 4; w++) { u64 o = wred[w][tid]; if (o > v) v = o; }
    packed_best[b * MN + mbase + tid] = v;
  }
}

// ---------------- K2: scatter override (sequential last-wins per batch) ----
__global__ void k_override(const u64* __restrict__ packed,
                           float* __restrict__ best_ovl,
                           int* __restrict__ best_idx)
{
  int b = threadIdx.x;
  if (b >= BN) return;
  for (int m = 0; m < MN; m++) {
    u64 pk = packed[b * MN + m];
    u32 pidx = 0xFFFFFFFFu - (u32)(pk & 0xFFFFFFFFull);
    best_idx[(size_t)b * PN + pidx] = m;
    best_ovl[(size_t)b * PN + pidx] = 1.0f;
  }
}

// ---------------- K3: fused loc loss + CE, 16 lanes per conf row -----------
// Each 16-lane group owns one row: lane l holds elements l, l+16, ..., l+80
// in 6 registers (wave load instr = 4 consecutive rows x 16 consecutive
// floats -> fully-consumed cache lines). Max/sum via 4x shfl_xor(width 16).
// No LDS tile, no barrier in the hot path, ~40 VGPR -> full occupancy.
__global__ __launch_bounds__(256)
void k_big(const f4* __restrict__ loc_preds,
           const float* __restrict__ conf_preds,
           const f4* __restrict__ priors,
           const f4* __restrict__ gt_boxes,
           const int* __restrict__ gt_labels,
           const float* __restrict__ best_ovl,
           const int* __restrict__ best_idx,
           float* __restrict__ ce_neg,
           int* __restrict__ pos_cnt,
           int* __restrict__ num_pos,
           double* __restrict__ acc)
{
  const int t = threadIdx.x;
  const int l = t & 15;
  const int row = blockIdx.x * 16 + (t >> 4);     // exact: BP = 16 * gridDim.x
  const int b = row / PN;                          // constant divisor -> magic mul
  const int p = row - b * PN;
  const float* rowp = conf_preds + (size_t)row * (size_t)CN;

  // load 6 strided elements into registers
  float e[6];
#pragma unroll
  for (int i = 0; i < 6; i++) {
    const int idx = l + (i << 4);
    e[i] = (idx < CN) ? rowp[idx] : -3.0e38f;
  }
  // group max
  float mx = e[0];
#pragma unroll
  for (int i = 1; i < 6; i++) mx = fmaxf(mx, e[i]);
#pragma unroll
  for (int m = 1; m < 16; m <<= 1) mx = fmaxf(mx, __shfl_xor(mx, m, 16));
  // group sum of exp
  float s = 0.f;
#pragma unroll
  for (int i = 0; i < 6; i++) s += __expf(e[i] - mx);
#pragma unroll
  for (int m = 1; m < 16; m <<= 1) s += __shfl_xor(s, m, 16);

  float my_sl1 = 0.f, my_cep = 0.f; int my_pos = 0;
  if (l == 0) {
    const float ovl = best_ovl[row];
    const int gi  = best_idx[row];
    const bool pos = ovl > 0.5f;
    int cls = 0;
    if (pos) {
      cls = gt_labels[b * MN + gi];
      f4 g = gt_boxes[b * MN + gi];
      f4 pr = priors[p];
      float gx = (g.x + g.z) * 0.5f, gy = (g.y + g.w) * 0.5f;
      float gw = g.z - g.x, gh = g.w - g.y;
      f4 lp = loc_preds[row];
      float d0 = lp.x - (gx - pr.x) / pr.z;
      float d1 = lp.y - (gy - pr.y) / pr.w;
      float d2 = lp.z - logf(gw / pr.z);
      float d3 = lp.w - logf(gh / pr.w);
      my_sl1 = sl1f(d0) + sl1f(d1) + sl1f(d2) + sl1f(d3);
      my_pos = 1;
      atomicAdd(&pos_cnt[b], 1);   // per-row: block may straddle two batches
    }
    const float xt = rowp[cls];                  // L1 hit (line already fetched)
    float ce = fmaxf(mx + logf(s) - xt, 0.0f);   // sign-free bits for radix select
    if (pos) { my_cep = ce; ce_neg[row] = 0.0f; }
    else     { ce_neg[row] = ce; }
  }

  // block reduce (double) -> one atomic set per block (b-independent sums)
  double dsl = (double)my_sl1, dce = (double)my_cep;
  int pc = my_pos;
#pragma unroll
  for (int off = 1; off < 64; off <<= 1) {
    dsl += __shfl_xor(dsl, off, 64);
    dce += __shfl_xor(dce, off, 64);
    pc  += __shfl_xor(pc, off, 64);
  }
  __shared__ double ssl[4], sce[4]; __shared__ int spc[4];
  const int wv = t >> 6;
  if ((t & 63) == 0) { ssl[wv] = dsl; sce[wv] = dce; spc[wv] = pc; }
  __syncthreads();
  if (t == 0) {
    double a = ssl[0] + ssl[1] + ssl[2] + ssl[3];
    double c = sce[0] + sce[1] + sce[2] + sce[3];
    int q = spc[0] + spc[1] + spc[2] + spc[3];
    if (q) {
      atomicAdd(&acc[0], a);
      atomicAdd(&acc[1], c);
      atomicAdd(num_pos, q);
    }
  }
}

// ---------------- K4: per-batch exact top-k sum via radix select ------------
__global__ __launch_bounds__(1024)
void k_topk(const float* __restrict__ ce_neg,
            const int* __restrict__ pos_cnt,
            double* __restrict__ acc)
{
  const int b = blockIdx.x;
  const float* row = ce_neg + (size_t)b * PN;
  int k = pos_cnt[b] * 3;
  if (k < 1) k = 1;
  if (k > PN) k = PN;

  const int tid = threadIdx.x;
  const int wv = tid >> 6;
  __shared__ u32 hist[16][256];
  __shared__ u32 sh_prefix; __shared__ int sh_rem;

  u32 prefix = 0; int rem = k;
  for (int shift = 24; shift >= 0; shift -= 8) {
    for (int i = tid; i < 16 * 256; i += blockDim.x) ((u32*)hist)[i] = 0;
    __syncthreads();
    const u32 pmask = (shift == 24) ? 0u : (0xFFFFFFFFu << (shift + 8));
    for (int p = tid; p < PN; p += blockDim.x) {
      u32 u = __float_as_uint(row[p]);
      if ((u & pmask) == (prefix & pmask))
        atomicAdd(&hist[wv][(u >> shift) & 255], 1u);
    }
    __syncthreads();
    if (tid < 256) {
      u32 c = 0;
#pragma unroll
      for (int w = 0; w < 16; w++) c += hist[w][tid];
      hist[0][tid] = c;
    }
    __syncthreads();
    if (tid == 0) {
      u32 c = 0; int d = 255;
      for (; d >= 0; d--) { c += hist[0][d]; if ((int)c >= rem) break; }
      if (d < 0) d = 0;
      sh_prefix = prefix | ((u32)d << shift);
      sh_rem = rem - (int)(c - hist[0][d]);
    }
    __syncthreads();
    prefix = sh_prefix; rem = sh_rem;
    __syncthreads();
  }

  const float vstar = __uint_as_float(prefix);
  double sg = 0.0;
  for (int p = tid; p < PN; p += blockDim.x) {
    float v = row[p];
    if (__float_as_uint(v) > prefix) sg += (double)v;
  }
#pragma unroll
  for (int off = 1; off < 64; off <<= 1) sg += __shfl_xor(sg, off, 64);
  __shared__ double sred[16];
  if ((tid & 63) == 0) sred[wv] = sg;
  __syncthreads();
  if (tid == 0) {
    double tacc = 0;
    for (int w = 0; w < 16; w++) tacc += sred[w];
    tacc += (double)rem * (double)vstar;   // ties at v* contribute identically
    atomicAdd(&acc[2], tacc);
  }
}

// ---------------- K5: finalize ----------------
__global__ void k_final(const double* __restrict__ acc,
                        const int* __restrict__ num_pos,
                        float* __restrict__ out)
{
  int np = *num_pos; if (np < 1) np = 1;
  out[0] = (float)((acc[0] + acc[1] + acc[2]) / (double)np);
}

extern "C" void kernel_launch(void* const* d_in, const int* in_sizes, int n_in,
                              void* d_out, int out_size, void* d_ws, size_t ws_size,
                              hipStream_t stream)
{
  const f4*    loc    = (const f4*)d_in[0];
  const float* conf   = (const float*)d_in[1];
  const f4*    priors = (const f4*)d_in[2];
  const f4*    gt     = (const f4*)d_in[3];
  const int*   labels = (const int*)d_in[4];

  char* ws = (char*)d_ws;
  float* ce_neg   = (float*)(ws);
  float* best_ovl = (float*)(ws + OFF_OVL);
  int*   best_idx = (int*)(ws + OFF_IDX);
  u64*   packed   = (u64*)(ws + OFF_PACK);
  int*   pos_cnt  = (int*)(ws + OFF_PCNT);
  int*   num_pos  = (int*)(ws + OFF_NP);
  double* acc     = (double*)(ws + OFF_ACC);

  k_zero<<<1, 128, 0, stream>>>((u32*)(ws + ZERO_OFF));
  k_prior_best<<<dim3((PN + 255) / 256, BN), 256, 0, stream>>>(priors, gt, best_ovl, best_idx);
  k_gt_best<<<dim3(MN / MG, BN), 256, 0, stream>>>(priors, gt, packed);
  k_override<<<1, 64, 0, stream>>>(packed, best_ovl, best_idx);
  k_big<<<dim3((BN * PN) / 16), 256, 0, stream>>>(loc, conf, priors, gt, labels,
                                                  best_ovl, best_idx, ce_neg,
                                                  pos_cnt, num_pos, acc);
  k_topk<<<BN, 1024, 0, stream>>>(ce_neg, pos_cnt, acc);
  k_final<<<1, 1, 0, stream>>>(acc, num_pos, (float*)d_out);
}

// Round 7
// 416.869 us; speedup vs baseline: 6.7222x; 6.7222x over previous
//
#include <hip/hip_runtime.h>
#include <stdint.h>

#define PN 24564
#define BN 64
#define MN 32
#define CN 81
#define MG 4       // gt boxes per block in k_gt_best

typedef float f4 __attribute__((ext_vector_type(4)));
typedef unsigned long long u64;
typedef unsigned int u32;

// ---------------- workspace layout ----------------
constexpr size_t SZ_BP4   = (size_t)BN * PN * 4;        // 6,288,384
constexpr size_t OFF_OVL  = SZ_BP4;                     // best_ovl f32
constexpr size_t OFF_IDX  = 2 * SZ_BP4;                 // best_idx i32
constexpr size_t OFF_PACK = 3 * SZ_BP4;                 // packed u64 [BN*MN]
constexpr size_t SZ_PACK  = (size_t)BN * MN * 8;        // 16,384
constexpr size_t OFF_PCNT = OFF_PACK + SZ_PACK;         // per-batch pos count (BN i32)
constexpr size_t OFF_NP   = OFF_PCNT + BN * 4;          // global num_pos
constexpr size_t OFF_ACC  = OFF_NP + 8;                 // 3 doubles
constexpr size_t ZERO_OFF = OFF_PCNT;
constexpr size_t ZERO_WORDS = (BN * 4 + 8 + 24) / 4;    // 72 u32 words

__device__ __forceinline__ float sl1f(float d) {
  float ad = fabsf(d);
  return ad < 1.0f ? 0.5f * d * d : ad - 0.5f;
}

__device__ __forceinline__ u64 shfl_xor_u64(u64 v, int m) {
  u32 lo = (u32)v, hi = (u32)(v >> 32);
  lo = (u32)__shfl_xor((int)lo, m, 64);
  hi = (u32)__shfl_xor((int)hi, m, 64);
  return ((u64)hi << 32) | lo;
}

// ---------------- K0: zero the accumulator tail ----------------
__global__ void k_zero(u32* __restrict__ tail)
{
  if (threadIdx.x < ZERO_WORDS) tail[threadIdx.x] = 0u;
}

// ---------------- K1a: per-prior best gt (max/argmax over m) ----------------
__global__ __launch_bounds__(256)
void k_prior_best(const f4* __restrict__ priors,
                  const f4* __restrict__ gt_boxes,
                  float* __restrict__ best_ovl,
                  int* __restrict__ best_idx)
{
  const int b = blockIdx.y;
  const int tid = threadIdx.x;
  __shared__ f4 gt[MN];
  __shared__ float ga[MN];
  if (tid < MN) {
    f4 g = gt_boxes[b * MN + tid];
    gt[tid] = g;
    ga[tid] = (g.z - g.x) * (g.w - g.y);
  }
  __syncthreads();
  const int p = blockIdx.x * 256 + tid;
  if (p >= PN) return;
  f4 pr = priors[p];
  float px0 = pr.x - pr.z * 0.5f;
  float py0 = pr.y - pr.w * 0.5f;
  float px1 = pr.x + pr.z * 0.5f;
  float py1 = pr.y + pr.w * 0.5f;
  float pa  = (px1 - px0) * (py1 - py0);
  float bov = -1.0f; int bi = 0;
#pragma unroll
  for (int m = 0; m < MN; m++) {
    f4 g = gt[m];
    float iw = fmaxf(fminf(px1, g.z) - fmaxf(px0, g.x), 0.0f);
    float ih = fmaxf(fminf(py1, g.w) - fmaxf(py0, g.y), 0.0f);
    float inter = iw * ih;
    float iou = inter / (pa + ga[m] - inter);
    if (iou > bov) { bov = iou; bi = m; }
  }
  best_ovl[(size_t)b * PN + p] = bov;
  best_idx[(size_t)b * PN + p] = bi;
}

// ---------------- K1b: per-gt best prior (argmax over p), 4 gt per block ----
__global__ __launch_bounds__(256)
void k_gt_best(const f4* __restrict__ priors,
               const f4* __restrict__ gt_boxes,
               u64* __restrict__ packed_best)
{
  const int b = blockIdx.y;
  const int mbase = blockIdx.x * MG;
  const int tid = threadIdx.x;

  f4 g[MG]; float ga[MG];
#pragma unroll
  for (int j = 0; j < MG; j++) {
    g[j] = gt_boxes[b * MN + mbase + j];
    ga[j] = (g[j].z - g[j].x) * (g[j].w - g[j].y);
  }

  u64 best[MG];
#pragma unroll
  for (int j = 0; j < MG; j++) best[j] = 0ull;

  for (int p = tid; p < PN; p += 256) {
    f4 pr = priors[p];
    float px0 = pr.x - pr.z * 0.5f;
    float py0 = pr.y - pr.w * 0.5f;
    float px1 = pr.x + pr.z * 0.5f;
    float py1 = pr.y + pr.w * 0.5f;
    float pa  = (px1 - px0) * (py1 - py0);
    u32 key = 0xFFFFFFFFu - (u32)p;  // larger key = smaller p -> first-occurrence ties
#pragma unroll
    for (int j = 0; j < MG; j++) {
      float iw = fmaxf(fminf(px1, g[j].z) - fmaxf(px0, g[j].x), 0.0f);
      float ih = fmaxf(fminf(py1, g[j].w) - fmaxf(py0, g[j].y), 0.0f);
      float inter = iw * ih;
      float iou = inter / (pa + ga[j] - inter);
      u64 pk = ((u64)__float_as_uint(iou) << 32) | key;
      if (pk > best[j]) best[j] = pk;
    }
  }

  __shared__ u64 wred[4][MG];
  const int lane = tid & 63, wv = tid >> 6;
#pragma unroll
  for (int j = 0; j < MG; j++) {
    u64 v = best[j];
#pragma unroll
    for (int off = 1; off < 64; off <<= 1) {
      u64 o = shfl_xor_u64(v, off);
      if (o > v) v = o;
    }
    if (lane == 0) wred[wv][j] = v;
  }
  __syncthreads();
  if (tid < MG) {
    u64 v = wred[0][tid];
#pragma unroll
    for (int w = 1; w < 4; w++) { u64 o = wred[w][tid]; if (o > v) v = o; }
    packed_best[b * MN + mbase + tid] = v;
  }
}

// ---------------- K2: scatter override (sequential last-wins per batch) ----
__global__ void k_override(const u64* __restrict__ packed,
                           float* __restrict__ best_ovl,
                           int* __restrict__ best_idx)
{
  int b = threadIdx.x;
  if (b >= BN) return;
  for (int m = 0; m < MN; m++) {
    u64 pk = packed[b * MN + m];
    u32 pidx = 0xFFFFFFFFu - (u32)(pk & 0xFFFFFFFFull);
    best_idx[(size_t)b * PN + pidx] = m;
    best_ovl[(size_t)b * PN + pidx] = 1.0f;
  }
}

// ---------------- K3: fused loc loss + CE, full-row register preload -------
// Thread-per-row (round-2 structure, empirically best) but with the ENTIRE
// 81-float row preloaded into registers as 21 back-to-back independent
// loads (deep MLP; ~21.5 KB in flight per wave). Bookkeeping loads issue
// first so their use doesn't drain the row loads. Two-pass max/exp over
// registers; negatives take xt from a register (cls==0).
__global__ __launch_bounds__(256)
void k_big(const f4* __restrict__ loc_preds,
           const float* __restrict__ conf_preds,
           const f4* __restrict__ priors,
           const f4* __restrict__ gt_boxes,
           const int* __restrict__ gt_labels,
           const float* __restrict__ best_ovl,
           const int* __restrict__ best_idx,
           float* __restrict__ ce_neg,
           int* __restrict__ pos_cnt,
           int* __restrict__ num_pos,
           double* __restrict__ acc)
{
  const int b = blockIdx.y;
  const int p = blockIdx.x * blockDim.x + threadIdx.x;
  float my_sl1 = 0.f, my_cep = 0.f; int my_pos = 0;
  if (p < PN) {
    const size_t rp = (size_t)b * PN + p;
    // bookkeeping loads first: their consumption waits only on themselves
    const float ovl = best_ovl[rp];
    const int gi = best_idx[rp];
    // issue the whole conf row: 20 x dwordx4 + 1 scalar, all independent
    const float* row = conf_preds + rp * (size_t)CN;
    const f4* vrow = (const f4*)row;
    f4 v[20];
#pragma unroll
    for (int i = 0; i < 20; i++) v[i] = vrow[i];
    float last = row[80];
    __builtin_amdgcn_sched_barrier(0);   // keep all loads ahead of compute

    // ---- pass 1: max (4 parallel chains) ----
    float c0 = last, c1 = -3.0e38f, c2 = -3.0e38f, c3 = -3.0e38f;
#pragma unroll
    for (int i = 0; i < 20; i += 4) {
      c0 = fmaxf(c0, fmaxf(fmaxf(v[i].x, v[i].y), fmaxf(v[i].z, v[i].w)));
      c1 = fmaxf(c1, fmaxf(fmaxf(v[i+1].x, v[i+1].y), fmaxf(v[i+1].z, v[i+1].w)));
      c2 = fmaxf(c2, fmaxf(fmaxf(v[i+2].x, v[i+2].y), fmaxf(v[i+2].z, v[i+2].w)));
      c3 = fmaxf(c3, fmaxf(fmaxf(v[i+3].x, v[i+3].y), fmaxf(v[i+3].z, v[i+3].w)));
    }
    const float mx = fmaxf(fmaxf(c0, c1), fmaxf(c2, c3));

    // ---- pass 2: sum of exp (4 accumulators) ----
    float s0 = __expf(last - mx), s1 = 0.f, s2 = 0.f, s3 = 0.f;
#pragma unroll
    for (int i = 0; i < 20; i++) {
      s0 += __expf(v[i].x - mx);
      s1 += __expf(v[i].y - mx);
      s2 += __expf(v[i].z - mx);
      s3 += __expf(v[i].w - mx);
    }
    const float s = (s0 + s1) + (s2 + s3);

    // ---- pos bookkeeping (rare lanes) ----
    const bool pos = ovl > 0.5f;
    float xt = v[0].x;                    // cls == 0 for negatives
    if (pos) {
      const int cls = gt_labels[b * MN + gi];
      xt = row[cls];                      // L1/L2 hit: line just fetched
      f4 g = gt_boxes[b * MN + gi];
      f4 pr = priors[p];
      float gx = (g.x + g.z) * 0.5f, gy = (g.y + g.w) * 0.5f;
      float gw = g.z - g.x, gh = g.w - g.y;
      f4 lp = loc_preds[rp];
      float d0 = lp.x - (gx - pr.x) / pr.z;
      float d1 = lp.y - (gy - pr.y) / pr.w;
      float d2 = lp.z - logf(gw / pr.z);
      float d3 = lp.w - logf(gh / pr.w);
      my_sl1 = sl1f(d0) + sl1f(d1) + sl1f(d2) + sl1f(d3);
      my_pos = 1;
    }
    float ce = mx + logf(s) - xt;
    ce = fmaxf(ce, 0.0f);   // keep bits sign-free for radix select
    if (pos) { my_cep = ce; ce_neg[rp] = 0.0f; }
    else     { ce_neg[rp] = ce; }
  }

  // block reduce (double) -> one atomic set per block
  double dsl = (double)my_sl1, dce = (double)my_cep;
  int pc = my_pos;
#pragma unroll
  for (int off = 1; off < 64; off <<= 1) {
    dsl += __shfl_xor(dsl, off, 64);
    dce += __shfl_xor(dce, off, 64);
    pc  += __shfl_xor(pc, off, 64);
  }
  __shared__ double ssl[4], sce[4]; __shared__ int spc[4];
  const int lane = threadIdx.x & 63, wv = threadIdx.x >> 6;
  if (lane == 0) { ssl[wv] = dsl; sce[wv] = dce; spc[wv] = pc; }
  __syncthreads();
  if (threadIdx.x == 0) {
    double a = ssl[0] + ssl[1] + ssl[2] + ssl[3];
    double c = sce[0] + sce[1] + sce[2] + sce[3];
    int q = spc[0] + spc[1] + spc[2] + spc[3];
    if (q) {
      atomicAdd(&acc[0], a);
      atomicAdd(&acc[1], c);
      atomicAdd(num_pos, q);
      atomicAdd(&pos_cnt[b], q);
    }
  }
}

// ---------------- K4: per-batch exact top-k sum via radix select ------------
__global__ __launch_bounds__(1024)
void k_topk(const float* __restrict__ ce_neg,
            const int* __restrict__ pos_cnt,
            double* __restrict__ acc)
{
  const int b = blockIdx.x;
  const float* row = ce_neg + (size_t)b * PN;
  int k = pos_cnt[b] * 3;
  if (k < 1) k = 1;
  if (k > PN) k = PN;

  const int tid = threadIdx.x;
  const int wv = tid >> 6;
  __shared__ u32 hist[16][256];
  __shared__ u32 sh_prefix; __shared__ int sh_rem;

  u32 prefix = 0; int rem = k;
  for (int shift = 24; shift >= 0; shift -= 8) {
    for (int i = tid; i < 16 * 256; i += blockDim.x) ((u32*)hist)[i] = 0;
    __syncthreads();
    const u32 pmask = (shift == 24) ? 0u : (0xFFFFFFFFu << (shift + 8));
    for (int p = tid; p < PN; p += blockDim.x) {
      u32 u = __float_as_uint(row[p]);
      if ((u & pmask) == (prefix & pmask))
        atomicAdd(&hist[wv][(u >> shift) & 255], 1u);
    }
    __syncthreads();
    if (tid < 256) {
      u32 c = 0;
#pragma unroll
      for (int w = 0; w < 16; w++) c += hist[w][tid];
      hist[0][tid] = c;
    }
    __syncthreads();
    if (tid == 0) {
      u32 c = 0; int d = 255;
      for (; d >= 0; d--) { c += hist[0][d]; if ((int)c >= rem) break; }
      if (d < 0) d = 0;
      sh_prefix = prefix | ((u32)d << shift);
      sh_rem = rem - (int)(c - hist[0][d]);
    }
    __syncthreads();
    prefix = sh_prefix; rem = sh_rem;
    __syncthreads();
  }

  const float vstar = __uint_as_float(prefix);
  double sg = 0.0;
  for (int p = tid; p < PN; p += blockDim.x) {
    float v = row[p];
    if (__float_as_uint(v) > prefix) sg += (double)v;
  }
#pragma unroll
  for (int off = 1; off < 64; off <<= 1) sg += __shfl_xor(sg, off, 64);
  __shared__ double sred[16];
  if ((tid & 63) == 0) sred[wv] = sg;
  __syncthreads();
  if (tid == 0) {
    double tacc = 0;
    for (int w = 0; w < 16; w++) tacc += sred[w];
    tacc += (double)rem * (double)vstar;   // ties at v* contribute identically
    atomicAdd(&acc[2], tacc);
  }
}

// ---------------- K5: finalize ----------------
__global__ void k_final(const double* __restrict__ acc,
                        const int* __restrict__ num_pos,
                        float* __restrict__ out)
{
  int np = *num_pos; if (np < 1) np = 1;
  out[0] = (float)((acc[0] + acc[1] + acc[2]) / (double)np);
}

extern "C" void kernel_launch(void* const* d_in, const int* in_sizes, int n_in,
                              void* d_out, int out_size, void* d_ws, size_t ws_size,
                              hipStream_t stream)
{
  const f4*    loc    = (const f4*)d_in[0];
  const float* conf   = (const float*)d_in[1];
  const f4*    priors = (const f4*)d_in[2];
  const f4*    gt     = (const f4*)d_in[3];
  const int*   labels = (const int*)d_in[4];

  char* ws = (char*)d_ws;
  float* ce_neg   = (float*)(ws);
  float* best_ovl = (float*)(ws + OFF_OVL);
  int*   best_idx = (int*)(ws + OFF_IDX);
  u64*   packed   = (u64*)(ws + OFF_PACK);
  int*   pos_cnt  = (int*)(ws + OFF_PCNT);
  int*   num_pos  = (int*)(ws + OFF_NP);
  double* acc     = (double*)(ws + OFF_ACC);

  k_zero<<<1, 128, 0, stream>>>((u32*)(ws + ZERO_OFF));
  k_prior_best<<<dim3((PN + 255) / 256, BN), 256, 0, stream>>>(priors, gt, best_ovl, best_idx);
  k_gt_best<<<dim3(MN / MG, BN), 256, 0, stream>>>(priors, gt, packed);
  k_override<<<1, 64, 0, stream>>>(packed, best_ovl, best_idx);
  k_big<<<dim3((PN + 255) / 256, BN), 256, 0, stream>>>(loc, conf, priors, gt, labels,
                                                        best_ovl, best_idx, ce_neg,
                                                        pos_cnt, num_pos, acc);
  k_topk<<<BN, 1024, 0, stream>>>(ce_neg, pos_cnt, acc);
  k_final<<<1, 1, 0, stream>>>(acc, num_pos, (float*)d_out);
}